// Round 7
// baseline (390.501 us; speedup 1.0000x reference)
//
#include <hip/hip_runtime.h>
#include <math.h>

#define NROWS 65536
#define DDIM  64
#define KCODE 4096
#define NSPLIT 4
#define KSPL  (KCODE / NSPLIT)
#define STEPS (KSPL / 16)          // 64
#define SMASK (STEPS - 1)

// output layout (float offsets), concatenated in reference return order
#define O_Q    0           // quantized_st [B,T,D] = 4194304
#define O_LOSS 4194304     // loss scalar
#define O_IDX  4194305     // encoding_indices [B,T] = 65536 (floats)
#define O_NW   4259841     // new_weight [K,D] = 262144
#define O_CS   4521985     // cs [K] = 4096
#define O_NEW  4526081     // new_ema_w [K,D] = 262144

// scratch inside O_Q (dead once vq_gather2 writes Q rows; all consumers run
// before vq_gather2):
//   E_hi  : halves [0, 262144)  (fragment-tile order)
//   E_lo  : halves [262144, 524288)
//   A     : floats [262144, 327680)
//   B2    : floats [327680, 331776)
//   counts: u32 @ float offset 1000000 (4096)
//   offs  : u32 @ 1010000 (4096)
//   cursor: u32 @ 1020000 (4096)
//   order : u32 @ 1030000 (65536)
// scratch inside O_NW (clobbered only by vq_final):
//   keys  : u64[65536] at float offset O_NW+1
#define O_A      262144
#define O_B2     327680
#define O_CNT   1000000
#define O_OFF   1010000
#define O_CUR   1020000
#define O_ORD   1030000

typedef _Float16 f16x8 __attribute__((ext_vector_type(8)));
typedef float    f32x4 __attribute__((ext_vector_type(4)));

// ---------------- Kernel A: init + splits + norms + key/count init ----------------
__global__ __launch_bounds__(256)
void vq_prep(const float* __restrict__ x, const float* __restrict__ w,
             float* __restrict__ out, unsigned long long* __restrict__ keys,
             double* __restrict__ loss_acc) {
    int i = blockIdx.x * 256 + threadIdx.x;   // grid = 262144 threads exactly
    // ehi/elo stored in MFMA-fragment tile order (validated round 6):
    //   pos = tile*1024 + (j>>5)*512 + ((j>>3)&3)*128 + (k&15)*8 + (j&7)
    {
        const int k = i >> 6, j = i & 63;
        float E = w[i] * 4096.0f;             // scaled f16 split of codes
        _Float16 h = (_Float16)E;
        float r = E - (float)h;
        _Float16 lo = (_Float16)(r * 4096.0f);
        const size_t pos = (size_t)(k >> 4) * 1024 + (size_t)(j >> 5) * 512
                         + (size_t)((j >> 3) & 3) * 128 + (size_t)(k & 15) * 8
                         + (size_t)(j & 7);
        ((_Float16*)out)[pos] = h;
        ((_Float16*)out)[262144 + pos] = lo;
    }
    if (i < NROWS) keys[i] = 0xFFFFFFFFFFFFFFFFULL;
    if (i < KCODE) ((unsigned*)(out + O_CNT))[i] = 0u;
    // x-norms (EXACT same per-row summation order as validated rounds)
    if ((i & 3) == 0) {
        const int row = i >> 2;
        const float4* xr = (const float4*)(x + (size_t)row * DDIM);
        float ax = 0.f, ay = 0.f, az = 0.f, aw = 0.f;
        #pragma unroll
        for (int j = 0; j < 16; ++j) {
            float4 v = xr[j];
            ax += v.x * v.x; ay += v.y * v.y; az += v.z * v.z; aw += v.w * v.w;
        }
        out[O_A + row] = (ax + ay) + (az + aw);
    }
    // w-norms
    if ((i & 63) == 0) {
        const int k = i >> 6;
        const float4* wr = (const float4*)(w + (size_t)k * DDIM);
        float ax = 0.f, ay = 0.f, az = 0.f, aw = 0.f;
        #pragma unroll
        for (int j = 0; j < 16; ++j) {
            float4 v = wr[j];
            ax += v.x * v.x; ay += v.y * v.y; az += v.z * v.z; aw += v.w * v.w;
        }
        out[O_B2 + k] = (ax + ay) + (az + aw);
    }
    if (i == 0) *loss_acc = 0.0;
}

__device__ inline void split8(float4 a, float4 b, f16x8& hi, f16x8& lo) {
    float vv[8] = {a.x, a.y, a.z, a.w, b.x, b.y, b.z, b.w};
    #pragma unroll
    for (int j = 0; j < 8; ++j) {
        float X = vv[j] * 256.0f;           // x*2^8
        _Float16 h = (_Float16)X;
        float r = X - (float)h;             // exact (Sterbenz)
        hi[j] = h;
        lo[j] = (_Float16)(r * 4096.0f);    // residual*2^12
    }
}

// ---------------- Kernel B: MFMA fused score + argmin (validated round 6) ----------------
__global__ __launch_bounds__(256, 3)
void vq_argmin_mfma(const float* __restrict__ x,
                    const _Float16* __restrict__ ehi,
                    const _Float16* __restrict__ elo,
                    const float* __restrict__ Ag,
                    const float* __restrict__ b2g,
                    unsigned long long* __restrict__ keys) {
    __shared__ __align__(16) float b2sh[KSPL];
    const int tid = threadIdx.x;
    const int k0  = blockIdx.y * KSPL;
    ((float4*)b2sh)[tid] = ((const float4*)(b2g + k0))[tid];
    __syncthreads();

    const int l   = tid & 63;
    const int w   = tid >> 6;
    const int g   = l >> 4;
    const int c16 = l & 15;
    const int rowbase = blockIdx.x * 128 + w * 32;
    const int soff = blockIdx.x & SMASK;

    f16x8 xh[2][2], xl[2][2];
    #pragma unroll
    for (int r = 0; r < 2; ++r) {
        const float* xr = x + (size_t)(rowbase + r * 16 + c16) * DDIM + g * 8;
        float4 a0 = *(const float4*)(xr);
        float4 a1 = *(const float4*)(xr + 4);
        float4 a2 = *(const float4*)(xr + 32);
        float4 a3 = *(const float4*)(xr + 36);
        split8(a0, a1, xh[r][0], xl[r][0]);
        split8(a2, a3, xh[r][1], xl[r][1]);
    }
    float A_reg[2][4];
    #pragma unroll
    for (int r = 0; r < 2; ++r)
        #pragma unroll
        for (int v = 0; v < 4; ++v)
            A_reg[r][v] = Ag[rowbase + r * 16 + 4 * g + v];

    float bestv[2][4]; int bidx[2][4];
    #pragma unroll
    for (int r = 0; r < 2; ++r)
        #pragma unroll
        for (int v = 0; v < 4; ++v) { bestv[r][v] = INFINITY; bidx[r][v] = 0x7FFFFFFF; }

    const _Float16* pbh = ehi + (size_t)(k0 >> 4) * 1024 + (size_t)l * 8;
    const _Float16* pbl = elo + (size_t)(k0 >> 4) * 1024 + (size_t)l * 8;

    f16x8 bh0[2], bh1[2], bl0[2], bl1[2];
    float b2r[2];

#define LOADB(sl, stv) do {                                  \
        const size_t _o = (size_t)(stv) * 1024;              \
        bh0[sl] = *(const f16x8*)(pbh + _o);                 \
        bh1[sl] = *(const f16x8*)(pbh + _o + 512);           \
        bl0[sl] = *(const f16x8*)(pbl + _o);                 \
        bl1[sl] = *(const f16x8*)(pbl + _o + 512);           \
        b2r[sl] = b2sh[(stv) * 16 + c16];                    \
    } while (0)

#define COMP(sl, stv) do {                                                        \
        f32x4 acc1[2], acc2[2];                                                   \
        _Pragma("unroll")                                                         \
        for (int r = 0; r < 2; ++r) {                                             \
            acc1[r] = (f32x4){0.f, 0.f, 0.f, 0.f};                                \
            acc2[r] = (f32x4){0.f, 0.f, 0.f, 0.f};                                \
            acc1[r] = __builtin_amdgcn_mfma_f32_16x16x32_f16(xh[r][0], bh0[sl], acc1[r], 0, 0, 0); \
            acc1[r] = __builtin_amdgcn_mfma_f32_16x16x32_f16(xh[r][1], bh1[sl], acc1[r], 0, 0, 0); \
            acc2[r] = __builtin_amdgcn_mfma_f32_16x16x32_f16(xl[r][0], bh0[sl], acc2[r], 0, 0, 0); \
            acc2[r] = __builtin_amdgcn_mfma_f32_16x16x32_f16(xl[r][1], bh1[sl], acc2[r], 0, 0, 0); \
            acc2[r] = __builtin_amdgcn_mfma_f32_16x16x32_f16(xh[r][0], bl0[sl], acc2[r], 0, 0, 0); \
            acc2[r] = __builtin_amdgcn_mfma_f32_16x16x32_f16(xh[r][1], bl1[sl], acc2[r], 0, 0, 0); \
        }                                                                         \
        const int _c = k0 + (stv) * 16 + c16;                                     \
        _Pragma("unroll")                                                         \
        for (int r = 0; r < 2; ++r) {                                             \
            _Pragma("unroll")                                                     \
            for (int v = 0; v < 4; ++v) {                                         \
                float dotc = fmaf(acc2[r][v], 0x1p-12f, acc1[r][v]);              \
                float t = A_reg[r][v] + b2r[sl];                                  \
                float sc = fmaf(dotc, -0x1p-19f, t);                              \
                if (sc < bestv[r][v] ||                                           \
                    (sc == bestv[r][v] && _c < bidx[r][v])) {                     \
                    bestv[r][v] = sc; bidx[r][v] = _c;                            \
                }                                                                 \
            }                                                                     \
        }                                                                         \
    } while (0)

    { const int st = soff & SMASK;       LOADB(0, st); }
    { const int st = (soff + 1) & SMASK; LOADB(1, st); }

    #pragma unroll 1
    for (int s = 0; s < STEPS; s += 2) {
        { const int st = (soff + s) & SMASK;     COMP(0, st); }
        { const int st = (soff + s + 2) & SMASK; LOADB(0, st); }
        { const int st = (soff + s + 1) & SMASK; COMP(1, st); }
        { const int st = (soff + s + 3) & SMASK; LOADB(1, st); }
    }
#undef LOADB
#undef COMP

    #pragma unroll
    for (int off = 1; off < 16; off <<= 1) {
        #pragma unroll
        for (int r = 0; r < 2; ++r)
            #pragma unroll
            for (int v = 0; v < 4; ++v) {
                float ob = __shfl_xor(bestv[r][v], off);
                int   oi = __shfl_xor(bidx[r][v], off);
                if (ob < bestv[r][v] || (ob == bestv[r][v] && oi < bidx[r][v])) {
                    bestv[r][v] = ob; bidx[r][v] = oi;
                }
            }
    }
    if (c16 == 0) {
        #pragma unroll
        for (int r = 0; r < 2; ++r)
            #pragma unroll
            for (int v = 0; v < 4; ++v) {
                const int row = rowbase + r * 16 + 4 * g + v;
                unsigned long long key =
                    ((unsigned long long)__float_as_uint(bestv[r][v]) << 32) |
                    (unsigned)bidx[r][v];
                atomicMin(&keys[row], key);
            }
    }
}

// ---------------- Kernel H: LDS histogram of codes ----------------
__global__ __launch_bounds__(1024)
void vq_hist(const unsigned long long* __restrict__ keys,
             unsigned* __restrict__ counts) {
    __shared__ unsigned h[KCODE];
    const int tid = threadIdx.x;
    #pragma unroll
    for (int j = 0; j < 4; ++j) h[tid + j * 1024] = 0u;
    __syncthreads();
    const int row = blockIdx.x * 1024 + tid;      // grid 64 x 1024
    const unsigned k = (unsigned)(keys[row] & 0xFFFFFFFFu);
    atomicAdd(&h[k], 1u);
    __syncthreads();
    #pragma unroll
    for (int j = 0; j < 4; ++j) {
        unsigned v = h[tid + j * 1024];
        if (v) atomicAdd(&counts[tid + j * 1024], v);
    }
}

// ---------------- Kernel S: exclusive scan -> offsets, cursor ----------------
__global__ __launch_bounds__(1024)
void vq_scan(const unsigned* __restrict__ counts,
             unsigned* __restrict__ offs, unsigned* __restrict__ cursor) {
    __shared__ unsigned red[1024];
    const int tid = threadIdx.x;
    unsigned c[4], tot = 0;
    #pragma unroll
    for (int j = 0; j < 4; ++j) { c[j] = counts[tid * 4 + j]; tot += c[j]; }
    red[tid] = tot;
    __syncthreads();
    for (int s = 1; s < 1024; s <<= 1) {
        unsigned v = (tid >= s) ? red[tid - s] : 0u;
        __syncthreads();
        red[tid] += v;
        __syncthreads();
    }
    unsigned base = red[tid] - tot;   // exclusive over thread blocks of 4
    #pragma unroll
    for (int j = 0; j < 4; ++j) {
        offs[tid * 4 + j] = base;
        cursor[tid * 4 + j] = base;
        base += c[j];
    }
}

// ---------------- Kernel T: scatter row ids into code-sorted order ----------------
__global__ __launch_bounds__(256)
void vq_scatter(const unsigned long long* __restrict__ keys,
                unsigned* __restrict__ cursor, unsigned* __restrict__ order) {
    const int row = blockIdx.x * 256 + threadIdx.x;
    const unsigned k = (unsigned)(keys[row] & 0xFFFFFFFFu);
    const unsigned slot = atomicAdd(&cursor[k], 1u);
    order[slot] = row;
}

// ---------------- Kernel W: per-code segment sum -> new_ema_w, counts ----------------
// one wave per code; lane l owns dimension l (coalesced 256B row reads)
__global__ __launch_bounds__(256)
void vq_dw(const float* __restrict__ x, const float* __restrict__ ema_w,
           const unsigned* __restrict__ counts, const unsigned* __restrict__ offs,
           const unsigned* __restrict__ order, float* __restrict__ out) {
    const int tid = threadIdx.x;
    const int lane = tid & 63;
    const int k = blockIdx.x * 4 + (tid >> 6);    // grid 1024 x 256
    const unsigned cnt = counts[k];
    const unsigned off = offs[k];
    float acc = 0.f;
    for (unsigned i = 0; i < cnt; ++i) {
        const unsigned row = order[off + i];
        acc += x[(size_t)row * DDIM + lane];
    }
    const float e = ema_w[(size_t)k * DDIM + lane];
    out[O_NEW + (size_t)k * DDIM + lane] = fmaf(0.01f, acc, 0.99f * e);
    if (lane == 0) out[O_CS + k] = (float)cnt;
}

// ---------------- Kernel C: gather + ST output + loss (atomic-free) ----------------
__global__ __launch_bounds__(256)
void vq_gather2(const float* __restrict__ x, const float* __restrict__ w,
                const unsigned long long* __restrict__ keys,
                float* __restrict__ out, double* __restrict__ loss_acc) {
    const int tid = threadIdx.x;
    const int l16 = tid & 15;
    const int row = blockIdx.x * 16 + (tid >> 4);
    const int k = (int)(unsigned)(keys[row] & 0xFFFFFFFFu);
    if (l16 == 0) out[O_IDX + row] = (float)k;

    const float4 w4 = ((const float4*)(w + (size_t)k * DDIM))[l16];
    const float4 x4 = ((const float4*)(x + (size_t)row * DDIM))[l16];
    float4 o;
    o.x = x4.x + (w4.x - x4.x);
    o.y = x4.y + (w4.y - x4.y);
    o.z = x4.z + (w4.z - x4.z);
    o.w = x4.w + (w4.w - x4.w);
    ((float4*)(out + O_Q + (size_t)row * DDIM))[l16] = o;
    float dx = w4.x - x4.x, dy = w4.y - x4.y, dz = w4.z - x4.z, dw_ = w4.w - x4.w;
    float e = dx * dx + dy * dy + dz * dz + dw_ * dw_;
    #pragma unroll
    for (int off = 32; off > 0; off >>= 1) e += __shfl_down(e, off);
    if ((tid & 63) == 0) atomicAdd(loss_acc, (double)e);
}

// ---------------- Kernel D: Laplace smoothing + loss write ----------------
__global__ __launch_bounds__(1024)
void vq_cs(const float* __restrict__ ecs, float* __restrict__ out,
           const double* __restrict__ loss_acc) {
    __shared__ float red[1024];
    const int tid = threadIdx.x;
    float cs[4];
    float local = 0.f;
    #pragma unroll
    for (int j = 0; j < 4; ++j) {
        int k = j * 1024 + tid;
        float cnt = out[O_CS + k];
        cs[j] = ecs[k] * 0.99f + 0.01f * cnt;
        local += cs[j];
    }
    red[tid] = local;
    for (int s = 512; s > 0; s >>= 1) {
        __syncthreads();
        if (tid < s) red[tid] += red[tid + s];
    }
    __syncthreads();
    const float n = red[0];
    const float denom = n + 0.04096f;
    #pragma unroll
    for (int j = 0; j < 4; ++j) {
        int k = j * 1024 + tid;
        out[O_CS + k] = (cs[j] + 1e-5f) / denom * n;
    }
    if (tid == 0) out[O_LOSS] = 1.25f * (float)(*loss_acc / 4194304.0);
}

// ---------------- Kernel E: new_weight = new_ema_w / cs ----------------
__global__ __launch_bounds__(256)
void vq_final(float* __restrict__ out) {
    int i = blockIdx.x * 256 + threadIdx.x;
    if (i >= KCODE * DDIM) return;
    int k = i >> 6;
    out[O_NW + i] = out[O_NEW + i] / out[O_CS + k];
}

extern "C" void kernel_launch(void* const* d_in, const int* in_sizes, int n_in,
                              void* d_out, int out_size, void* d_ws, size_t ws_size,
                              hipStream_t stream) {
    (void)in_sizes; (void)n_in; (void)out_size; (void)ws_size;
    const float* x    = (const float*)d_in[0];
    const float* w    = (const float*)d_in[1];
    const float* ecs  = (const float*)d_in[2];
    const float* emaw = (const float*)d_in[3];
    float* out = (float*)d_out;
    double* lacc = (double*)d_ws;

    const _Float16* ehi = (const _Float16*)out;
    const _Float16* elo = ((const _Float16*)out) + 262144;
    const float*    Ag  = out + O_A;
    unsigned long long* keys = (unsigned long long*)(out + O_NW + 1);
    unsigned* counts = (unsigned*)(out + O_CNT);
    unsigned* offs   = (unsigned*)(out + O_OFF);
    unsigned* cursor = (unsigned*)(out + O_CUR);
    unsigned* order  = (unsigned*)(out + O_ORD);

    vq_prep       <<<1024, 256, 0, stream>>>(x, w, out, keys, lacc);
    vq_argmin_mfma<<<dim3(512, NSPLIT), 256, 0, stream>>>(x, ehi, elo, Ag,
                                                          out + O_B2, keys);
    vq_hist       <<<64, 1024, 0, stream>>>(keys, counts);
    vq_scan       <<<1, 1024, 0, stream>>>(counts, offs, cursor);
    vq_scatter    <<<256, 256, 0, stream>>>(keys, cursor, order);
    vq_dw         <<<1024, 256, 0, stream>>>(x, emaw, counts, offs, order, out);
    vq_gather2    <<<4096, 256, 0, stream>>>(x, w, keys, out, lacc);
    vq_cs         <<<1, 1024, 0, stream>>>(ecs, out, lacc);
    vq_final      <<<1024, 256, 0, stream>>>(out);
}

// Round 8
// 198.316 us; speedup vs baseline: 1.9691x; 1.9691x over previous
//
#include <hip/hip_runtime.h>
#include <math.h>

#define NROWS 65536
#define DDIM  64
#define KCODE 4096
#define NSPLIT 4
#define KSPL  (KCODE / NSPLIT)
#define STEPS (KSPL / 16)          // 64
#define SMASK (STEPS - 1)

// output layout (float offsets), concatenated in reference return order
#define O_Q    0           // quantized_st [B,T,D] = 4194304
#define O_LOSS 4194304     // loss scalar
#define O_IDX  4194305     // encoding_indices [B,T] = 65536 (floats)
#define O_NW   4259841     // new_weight [K,D] = 262144
#define O_CS   4521985     // cs [K] = 4096
#define O_NEW  4526081     // new_ema_w [K,D] = 262144

// scratch inside O_Q (dead once vq_gather2 writes Q rows; all consumers run
// before vq_gather2):
//   E_hi  : halves [0, 262144)  (fragment-tile order)
//   E_lo  : halves [262144, 524288)
//   A     : floats [262144, 327680)
//   B2    : floats [327680, 331776)
//   counts: u32 @ float offset 1000000 (4096)
//   offs  : u32 @ 1010000 (4096)
//   cursor: u32 @ 1020000 (4096)
//   order : u32 @ 1030000 (65536)
// scratch inside O_NW (clobbered only by vq_final, which runs last):
//   keys  : u64[65536] at float offset O_NW+1
//   lpart : f32[16384] at float offset O_NW+131074 (per-wave loss partials)
#define O_A      262144
#define O_B2     327680
#define O_CNT   1000000
#define O_OFF   1010000
#define O_CUR   1020000
#define O_ORD   1030000
#define O_LP    (O_NW + 131074)

typedef _Float16 f16x8 __attribute__((ext_vector_type(8)));
typedef float    f32x4 __attribute__((ext_vector_type(4)));

// ---------------- Kernel A: init + splits + norms + key/count init ----------------
__global__ __launch_bounds__(256)
void vq_prep(const float* __restrict__ x, const float* __restrict__ w,
             float* __restrict__ out, unsigned long long* __restrict__ keys) {
    int i = blockIdx.x * 256 + threadIdx.x;   // grid = 262144 threads exactly
    // ehi/elo stored in MFMA-fragment tile order (validated round 6):
    //   pos = tile*1024 + (j>>5)*512 + ((j>>3)&3)*128 + (k&15)*8 + (j&7)
    {
        const int k = i >> 6, j = i & 63;
        float E = w[i] * 4096.0f;             // scaled f16 split of codes
        _Float16 h = (_Float16)E;
        float r = E - (float)h;
        _Float16 lo = (_Float16)(r * 4096.0f);
        const size_t pos = (size_t)(k >> 4) * 1024 + (size_t)(j >> 5) * 512
                         + (size_t)((j >> 3) & 3) * 128 + (size_t)(k & 15) * 8
                         + (size_t)(j & 7);
        ((_Float16*)out)[pos] = h;
        ((_Float16*)out)[262144 + pos] = lo;
    }
    if (i < NROWS) keys[i] = 0xFFFFFFFFFFFFFFFFULL;
    if (i < KCODE) ((unsigned*)(out + O_CNT))[i] = 0u;
    // x-norms (EXACT same per-row summation order as validated rounds)
    if ((i & 3) == 0) {
        const int row = i >> 2;
        const float4* xr = (const float4*)(x + (size_t)row * DDIM);
        float ax = 0.f, ay = 0.f, az = 0.f, aw = 0.f;
        #pragma unroll
        for (int j = 0; j < 16; ++j) {
            float4 v = xr[j];
            ax += v.x * v.x; ay += v.y * v.y; az += v.z * v.z; aw += v.w * v.w;
        }
        out[O_A + row] = (ax + ay) + (az + aw);
    }
    // w-norms
    if ((i & 63) == 0) {
        const int k = i >> 6;
        const float4* wr = (const float4*)(w + (size_t)k * DDIM);
        float ax = 0.f, ay = 0.f, az = 0.f, aw = 0.f;
        #pragma unroll
        for (int j = 0; j < 16; ++j) {
            float4 v = wr[j];
            ax += v.x * v.x; ay += v.y * v.y; az += v.z * v.z; aw += v.w * v.w;
        }
        out[O_B2 + k] = (ax + ay) + (az + aw);
    }
}

__device__ inline void split8(float4 a, float4 b, f16x8& hi, f16x8& lo) {
    float vv[8] = {a.x, a.y, a.z, a.w, b.x, b.y, b.z, b.w};
    #pragma unroll
    for (int j = 0; j < 8; ++j) {
        float X = vv[j] * 256.0f;           // x*2^8
        _Float16 h = (_Float16)X;
        float r = X - (float)h;             // exact (Sterbenz)
        hi[j] = h;
        lo[j] = (_Float16)(r * 4096.0f);    // residual*2^12
    }
}

// ---------------- Kernel B: MFMA fused score + argmin (validated round 6) ----------------
__global__ __launch_bounds__(256, 3)
void vq_argmin_mfma(const float* __restrict__ x,
                    const _Float16* __restrict__ ehi,
                    const _Float16* __restrict__ elo,
                    const float* __restrict__ Ag,
                    const float* __restrict__ b2g,
                    unsigned long long* __restrict__ keys) {
    __shared__ __align__(16) float b2sh[KSPL];
    const int tid = threadIdx.x;
    const int k0  = blockIdx.y * KSPL;
    ((float4*)b2sh)[tid] = ((const float4*)(b2g + k0))[tid];
    __syncthreads();

    const int l   = tid & 63;
    const int w   = tid >> 6;
    const int g   = l >> 4;
    const int c16 = l & 15;
    const int rowbase = blockIdx.x * 128 + w * 32;
    const int soff = blockIdx.x & SMASK;

    f16x8 xh[2][2], xl[2][2];
    #pragma unroll
    for (int r = 0; r < 2; ++r) {
        const float* xr = x + (size_t)(rowbase + r * 16 + c16) * DDIM + g * 8;
        float4 a0 = *(const float4*)(xr);
        float4 a1 = *(const float4*)(xr + 4);
        float4 a2 = *(const float4*)(xr + 32);
        float4 a3 = *(const float4*)(xr + 36);
        split8(a0, a1, xh[r][0], xl[r][0]);
        split8(a2, a3, xh[r][1], xl[r][1]);
    }
    float A_reg[2][4];
    #pragma unroll
    for (int r = 0; r < 2; ++r)
        #pragma unroll
        for (int v = 0; v < 4; ++v)
            A_reg[r][v] = Ag[rowbase + r * 16 + 4 * g + v];

    float bestv[2][4]; int bidx[2][4];
    #pragma unroll
    for (int r = 0; r < 2; ++r)
        #pragma unroll
        for (int v = 0; v < 4; ++v) { bestv[r][v] = INFINITY; bidx[r][v] = 0x7FFFFFFF; }

    const _Float16* pbh = ehi + (size_t)(k0 >> 4) * 1024 + (size_t)l * 8;
    const _Float16* pbl = elo + (size_t)(k0 >> 4) * 1024 + (size_t)l * 8;

    f16x8 bh0[2], bh1[2], bl0[2], bl1[2];
    float b2r[2];

#define LOADB(sl, stv) do {                                  \
        const size_t _o = (size_t)(stv) * 1024;              \
        bh0[sl] = *(const f16x8*)(pbh + _o);                 \
        bh1[sl] = *(const f16x8*)(pbh + _o + 512);           \
        bl0[sl] = *(const f16x8*)(pbl + _o);                 \
        bl1[sl] = *(const f16x8*)(pbl + _o + 512);           \
        b2r[sl] = b2sh[(stv) * 16 + c16];                    \
    } while (0)

#define COMP(sl, stv) do {                                                        \
        f32x4 acc1[2], acc2[2];                                                   \
        _Pragma("unroll")                                                         \
        for (int r = 0; r < 2; ++r) {                                             \
            acc1[r] = (f32x4){0.f, 0.f, 0.f, 0.f};                                \
            acc2[r] = (f32x4){0.f, 0.f, 0.f, 0.f};                                \
            acc1[r] = __builtin_amdgcn_mfma_f32_16x16x32_f16(xh[r][0], bh0[sl], acc1[r], 0, 0, 0); \
            acc1[r] = __builtin_amdgcn_mfma_f32_16x16x32_f16(xh[r][1], bh1[sl], acc1[r], 0, 0, 0); \
            acc2[r] = __builtin_amdgcn_mfma_f32_16x16x32_f16(xl[r][0], bh0[sl], acc2[r], 0, 0, 0); \
            acc2[r] = __builtin_amdgcn_mfma_f32_16x16x32_f16(xl[r][1], bh1[sl], acc2[r], 0, 0, 0); \
            acc2[r] = __builtin_amdgcn_mfma_f32_16x16x32_f16(xh[r][0], bl0[sl], acc2[r], 0, 0, 0); \
            acc2[r] = __builtin_amdgcn_mfma_f32_16x16x32_f16(xh[r][1], bl1[sl], acc2[r], 0, 0, 0); \
        }                                                                         \
        const int _c = k0 + (stv) * 16 + c16;                                     \
        _Pragma("unroll")                                                         \
        for (int r = 0; r < 2; ++r) {                                             \
            _Pragma("unroll")                                                     \
            for (int v = 0; v < 4; ++v) {                                         \
                float dotc = fmaf(acc2[r][v], 0x1p-12f, acc1[r][v]);              \
                float t = A_reg[r][v] + b2r[sl];                                  \
                float sc = fmaf(dotc, -0x1p-19f, t);                              \
                if (sc < bestv[r][v] ||                                           \
                    (sc == bestv[r][v] && _c < bidx[r][v])) {                     \
                    bestv[r][v] = sc; bidx[r][v] = _c;                            \
                }                                                                 \
            }                                                                     \
        }                                                                         \
    } while (0)

    { const int st = soff & SMASK;       LOADB(0, st); }
    { const int st = (soff + 1) & SMASK; LOADB(1, st); }

    #pragma unroll 1
    for (int s = 0; s < STEPS; s += 2) {
        { const int st = (soff + s) & SMASK;     COMP(0, st); }
        { const int st = (soff + s + 2) & SMASK; LOADB(0, st); }
        { const int st = (soff + s + 1) & SMASK; COMP(1, st); }
        { const int st = (soff + s + 3) & SMASK; LOADB(1, st); }
    }
#undef LOADB
#undef COMP

    #pragma unroll
    for (int off = 1; off < 16; off <<= 1) {
        #pragma unroll
        for (int r = 0; r < 2; ++r)
            #pragma unroll
            for (int v = 0; v < 4; ++v) {
                float ob = __shfl_xor(bestv[r][v], off);
                int   oi = __shfl_xor(bidx[r][v], off);
                if (ob < bestv[r][v] || (ob == bestv[r][v] && oi < bidx[r][v])) {
                    bestv[r][v] = ob; bidx[r][v] = oi;
                }
            }
    }
    if (c16 == 0) {
        #pragma unroll
        for (int r = 0; r < 2; ++r)
            #pragma unroll
            for (int v = 0; v < 4; ++v) {
                const int row = rowbase + r * 16 + 4 * g + v;
                unsigned long long key =
                    ((unsigned long long)__float_as_uint(bestv[r][v]) << 32) |
                    (unsigned)bidx[r][v];
                atomicMin(&keys[row], key);
            }
    }
}

// ---------------- Kernel H: LDS histogram of codes ----------------
__global__ __launch_bounds__(1024)
void vq_hist(const unsigned long long* __restrict__ keys,
             unsigned* __restrict__ counts) {
    __shared__ unsigned h[KCODE];
    const int tid = threadIdx.x;
    #pragma unroll
    for (int j = 0; j < 4; ++j) h[tid + j * 1024] = 0u;
    __syncthreads();
    const int row = blockIdx.x * 1024 + tid;      // grid 64 x 1024
    const unsigned k = (unsigned)(keys[row] & 0xFFFFFFFFu);
    atomicAdd(&h[k], 1u);
    __syncthreads();
    #pragma unroll
    for (int j = 0; j < 4; ++j) {
        unsigned v = h[tid + j * 1024];
        if (v) atomicAdd(&counts[tid + j * 1024], v);
    }
}

// ---------------- Kernel S: exclusive scan -> offsets, cursor ----------------
__global__ __launch_bounds__(1024)
void vq_scan(const unsigned* __restrict__ counts,
             unsigned* __restrict__ offs, unsigned* __restrict__ cursor) {
    __shared__ unsigned red[1024];
    const int tid = threadIdx.x;
    unsigned c[4], tot = 0;
    #pragma unroll
    for (int j = 0; j < 4; ++j) { c[j] = counts[tid * 4 + j]; tot += c[j]; }
    red[tid] = tot;
    __syncthreads();
    for (int s = 1; s < 1024; s <<= 1) {
        unsigned v = (tid >= s) ? red[tid - s] : 0u;
        __syncthreads();
        red[tid] += v;
        __syncthreads();
    }
    unsigned base = red[tid] - tot;   // exclusive over thread blocks of 4
    #pragma unroll
    for (int j = 0; j < 4; ++j) {
        offs[tid * 4 + j] = base;
        cursor[tid * 4 + j] = base;
        base += c[j];
    }
}

// ---------------- Kernel T: scatter row ids into code-sorted order ----------------
__global__ __launch_bounds__(256)
void vq_scatter(const unsigned long long* __restrict__ keys,
                unsigned* __restrict__ cursor, unsigned* __restrict__ order) {
    const int row = blockIdx.x * 256 + threadIdx.x;
    const unsigned k = (unsigned)(keys[row] & 0xFFFFFFFFu);
    const unsigned slot = atomicAdd(&cursor[k], 1u);
    order[slot] = row;
}

// ---------------- Kernel W: per-code segment sum -> new_ema_w, counts ----------------
// one wave per code; lane l owns dimension l (coalesced 256B row reads)
__global__ __launch_bounds__(256)
void vq_dw(const float* __restrict__ x, const float* __restrict__ ema_w,
           const unsigned* __restrict__ counts, const unsigned* __restrict__ offs,
           const unsigned* __restrict__ order, float* __restrict__ out) {
    const int tid = threadIdx.x;
    const int lane = tid & 63;
    const int k = blockIdx.x * 4 + (tid >> 6);    // grid 1024 x 256
    const unsigned cnt = counts[k];
    const unsigned off = offs[k];
    float acc = 0.f;
    for (unsigned i = 0; i < cnt; ++i) {
        const unsigned row = order[off + i];
        acc += x[(size_t)row * DDIM + lane];
    }
    const float e = ema_w[(size_t)k * DDIM + lane];
    out[O_NEW + (size_t)k * DDIM + lane] = fmaf(0.01f, acc, 0.99f * e);
    if (lane == 0) out[O_CS + k] = (float)cnt;
}

// ---------------- Kernel C: gather + ST output + loss partials (atomic-free) ----------------
__global__ __launch_bounds__(256)
void vq_gather2(const float* __restrict__ x, const float* __restrict__ w,
                const unsigned long long* __restrict__ keys,
                float* __restrict__ out, float* __restrict__ lpart) {
    const int tid = threadIdx.x;
    const int l16 = tid & 15;
    const int row = blockIdx.x * 16 + (tid >> 4);
    const int k = (int)(unsigned)(keys[row] & 0xFFFFFFFFu);
    if (l16 == 0) out[O_IDX + row] = (float)k;

    const float4 w4 = ((const float4*)(w + (size_t)k * DDIM))[l16];
    const float4 x4 = ((const float4*)(x + (size_t)row * DDIM))[l16];
    float4 o;
    o.x = x4.x + (w4.x - x4.x);
    o.y = x4.y + (w4.y - x4.y);
    o.z = x4.z + (w4.z - x4.z);
    o.w = x4.w + (w4.w - x4.w);
    ((float4*)(out + O_Q + (size_t)row * DDIM))[l16] = o;
    float dx = w4.x - x4.x, dy = w4.y - x4.y, dz = w4.z - x4.z, dw_ = w4.w - x4.w;
    float e = dx * dx + dy * dy + dz * dz + dw_ * dw_;
    #pragma unroll
    for (int off = 32; off > 0; off >>= 1) e += __shfl_down(e, off);
    // per-wave partial, coalesced store — no global atomic (round-7 fix:
    // 16K same-address f64 atomics serialized at ~12ns each = the 200us)
    if ((tid & 63) == 0) lpart[blockIdx.x * 4 + (tid >> 6)] = e;
}

// ---------------- Kernel D: loss reduce + Laplace smoothing ----------------
__global__ __launch_bounds__(1024)
void vq_cs(const float* __restrict__ ecs, const float* __restrict__ lpart,
           float* __restrict__ out) {
    __shared__ float red[1024];
    __shared__ double dred[1024];
    const int tid = threadIdx.x;
    // loss: 16384 partials, 16 per thread, double accumulate
    double dl = 0.0;
    #pragma unroll
    for (int j = 0; j < 16; ++j) dl += (double)lpart[j * 1024 + tid];
    dred[tid] = dl;
    float cs[4];
    float local = 0.f;
    #pragma unroll
    for (int j = 0; j < 4; ++j) {
        int k = j * 1024 + tid;
        float cnt = out[O_CS + k];
        cs[j] = ecs[k] * 0.99f + 0.01f * cnt;
        local += cs[j];
    }
    red[tid] = local;
    for (int s = 512; s > 0; s >>= 1) {
        __syncthreads();
        if (tid < s) { red[tid] += red[tid + s]; dred[tid] += dred[tid + s]; }
    }
    __syncthreads();
    const float n = red[0];
    const float denom = n + 0.04096f;
    #pragma unroll
    for (int j = 0; j < 4; ++j) {
        int k = j * 1024 + tid;
        out[O_CS + k] = (cs[j] + 1e-5f) / denom * n;
    }
    if (tid == 0) out[O_LOSS] = 1.25f * (float)(dred[0] / 4194304.0);
}

// ---------------- Kernel E: new_weight = new_ema_w / cs ----------------
__global__ __launch_bounds__(256)
void vq_final(float* __restrict__ out) {
    int i = blockIdx.x * 256 + threadIdx.x;
    if (i >= KCODE * DDIM) return;
    int k = i >> 6;
    out[O_NW + i] = out[O_NEW + i] / out[O_CS + k];
}

extern "C" void kernel_launch(void* const* d_in, const int* in_sizes, int n_in,
                              void* d_out, int out_size, void* d_ws, size_t ws_size,
                              hipStream_t stream) {
    (void)in_sizes; (void)n_in; (void)out_size; (void)d_ws; (void)ws_size;
    const float* x    = (const float*)d_in[0];
    const float* w    = (const float*)d_in[1];
    const float* ecs  = (const float*)d_in[2];
    const float* emaw = (const float*)d_in[3];
    float* out = (float*)d_out;

    const _Float16* ehi = (const _Float16*)out;
    const _Float16* elo = ((const _Float16*)out) + 262144;
    const float*    Ag  = out + O_A;
    unsigned long long* keys = (unsigned long long*)(out + O_NW + 1);
    unsigned* counts = (unsigned*)(out + O_CNT);
    unsigned* offs   = (unsigned*)(out + O_OFF);
    unsigned* cursor = (unsigned*)(out + O_CUR);
    unsigned* order  = (unsigned*)(out + O_ORD);
    float*    lpart  = out + O_LP;

    vq_prep       <<<1024, 256, 0, stream>>>(x, w, out, keys);
    vq_argmin_mfma<<<dim3(512, NSPLIT), 256, 0, stream>>>(x, ehi, elo, Ag,
                                                          out + O_B2, keys);
    vq_hist       <<<64, 1024, 0, stream>>>(keys, counts);
    vq_scan       <<<1, 1024, 0, stream>>>(counts, offs, cursor);
    vq_scatter    <<<256, 256, 0, stream>>>(keys, cursor, order);
    vq_dw         <<<1024, 256, 0, stream>>>(x, emaw, counts, offs, order, out);
    vq_gather2    <<<4096, 256, 0, stream>>>(x, w, keys, out, lpart);
    vq_cs         <<<1, 1024, 0, stream>>>(ecs, lpart, out);
    vq_final      <<<1024, 256, 0, stream>>>(out);
}

// Round 9
// 184.701 us; speedup vs baseline: 2.1142x; 1.0737x over previous
//
#include <hip/hip_runtime.h>
#include <math.h>

#define NROWS 65536
#define DDIM  64
#define KCODE 4096
#define NSPLIT 4
#define KSPL  (KCODE / NSPLIT)
#define STEPS (KSPL / 16)          // 64
#define SMASK (STEPS - 1)

// output layout (float offsets), concatenated in reference return order
#define O_Q    0           // quantized_st [B,T,D] = 4194304
#define O_LOSS 4194304     // loss scalar
#define O_IDX  4194305     // encoding_indices [B,T] = 65536 (floats)
#define O_NW   4259841     // new_weight [K,D] = 262144
#define O_CS   4521985     // cs [K] = 4096
#define O_NEW  4526081     // new_ema_w [K,D] = 262144

// scratch inside O_Q (dead once vq_gather2 writes Q rows):
//   E_hi  : halves [0, 262144)  (fragment-tile order)
//   E_lo  : halves [262144, 524288)
//   A     : floats [262144, 327680)
//   B2    : floats [327680, 331776)
//   counts: u32 @ 1000000; offs: u32 @ 1010000; cursor: u32 @ 1020000
//   order : u32 @ 1030000
// scratch inside O_NW (clobbered only by vq_final):
//   keys  : u64[65536] at float offset O_NW+1
//   lpart : f32[16384] at float offset O_NW+131074
#define O_A      262144
#define O_B2     327680
#define O_CNT   1000000
#define O_OFF   1010000
#define O_CUR   1020000
#define O_ORD   1030000
#define O_LP    (O_NW + 131074)

typedef _Float16 f16x8 __attribute__((ext_vector_type(8)));
typedef float    f32x4 __attribute__((ext_vector_type(4)));

// ---------------- Kernel A: init + splits + norms + key/count init ----------------
__global__ __launch_bounds__(256)
void vq_prep(const float* __restrict__ x, const float* __restrict__ w,
             float* __restrict__ out, unsigned long long* __restrict__ keys) {
    int i = blockIdx.x * 256 + threadIdx.x;   // grid = 262144 threads exactly
    // ehi/elo stored in MFMA-fragment tile order (validated round 6):
    //   pos = tile*1024 + (j>>5)*512 + ((j>>3)&3)*128 + (k&15)*8 + (j&7)
    {
        const int k = i >> 6, j = i & 63;
        float E = w[i] * 4096.0f;             // scaled f16 split of codes
        _Float16 h = (_Float16)E;
        float r = E - (float)h;
        _Float16 lo = (_Float16)(r * 4096.0f);
        const size_t pos = (size_t)(k >> 4) * 1024 + (size_t)(j >> 5) * 512
                         + (size_t)((j >> 3) & 3) * 128 + (size_t)(k & 15) * 8
                         + (size_t)(j & 7);
        ((_Float16*)out)[pos] = h;
        ((_Float16*)out)[262144 + pos] = lo;
    }
    if (i < NROWS) keys[i] = 0xFFFFFFFFFFFFFFFFULL;
    if (i < KCODE) ((unsigned*)(out + O_CNT))[i] = 0u;
    // x-norms (EXACT same per-row summation order as validated rounds)
    if ((i & 3) == 0) {
        const int row = i >> 2;
        const float4* xr = (const float4*)(x + (size_t)row * DDIM);
        float ax = 0.f, ay = 0.f, az = 0.f, aw = 0.f;
        #pragma unroll
        for (int j = 0; j < 16; ++j) {
            float4 v = xr[j];
            ax += v.x * v.x; ay += v.y * v.y; az += v.z * v.z; aw += v.w * v.w;
        }
        out[O_A + row] = (ax + ay) + (az + aw);
    }
    // w-norms
    if ((i & 63) == 0) {
        const int k = i >> 6;
        const float4* wr = (const float4*)(w + (size_t)k * DDIM);
        float ax = 0.f, ay = 0.f, az = 0.f, aw = 0.f;
        #pragma unroll
        for (int j = 0; j < 16; ++j) {
            float4 v = wr[j];
            ax += v.x * v.x; ay += v.y * v.y; az += v.z * v.z; aw += v.w * v.w;
        }
        out[O_B2 + k] = (ax + ay) + (az + aw);
    }
}

__device__ inline void split8(float4 a, float4 b, f16x8& hi, f16x8& lo) {
    float vv[8] = {a.x, a.y, a.z, a.w, b.x, b.y, b.z, b.w};
    #pragma unroll
    for (int j = 0; j < 8; ++j) {
        float X = vv[j] * 256.0f;           // x*2^8
        _Float16 h = (_Float16)X;
        float r = X - (float)h;             // exact (Sterbenz)
        hi[j] = h;
        lo[j] = (_Float16)(r * 4096.0f);    // residual*2^12
    }
}

// ---------------- Kernel B: MFMA fused score + argmin (lean issue path) ----------------
// Round-9 changes (instruction-count diet; numerics byte-identical):
//  - linear scan (no stagger) -> per-lane code index strictly increasing ->
//    strict < IS the lowest-index tie-break; 3 compare/logic ops per score removed
//  - 32-bit running offsets for the 4 loads (one offset serves both tables)
//  - incremental code index (cbase += 16) and b2 index (+= 32 per slot)
__global__ __launch_bounds__(256, 3)
void vq_argmin_mfma(const float* __restrict__ x,
                    const _Float16* __restrict__ ehi,
                    const _Float16* __restrict__ elo,
                    const float* __restrict__ Ag,
                    const float* __restrict__ b2g,
                    unsigned long long* __restrict__ keys) {
    __shared__ __align__(16) float b2sh[KSPL];
    const int tid = threadIdx.x;
    const int k0  = blockIdx.y * KSPL;
    ((float4*)b2sh)[tid] = ((const float4*)(b2g + k0))[tid];
    __syncthreads();

    const int l   = tid & 63;
    const int w   = tid >> 6;
    const int g   = l >> 4;
    const int c16 = l & 15;
    const int rowbase = blockIdx.x * 128 + w * 32;

    f16x8 xh[2][2], xl[2][2];
    #pragma unroll
    for (int r = 0; r < 2; ++r) {
        const float* xr = x + (size_t)(rowbase + r * 16 + c16) * DDIM + g * 8;
        float4 a0 = *(const float4*)(xr);
        float4 a1 = *(const float4*)(xr + 4);
        float4 a2 = *(const float4*)(xr + 32);
        float4 a3 = *(const float4*)(xr + 36);
        split8(a0, a1, xh[r][0], xl[r][0]);
        split8(a2, a3, xh[r][1], xl[r][1]);
    }
    float A_reg[2][4];
    #pragma unroll
    for (int r = 0; r < 2; ++r)
        #pragma unroll
        for (int v = 0; v < 4; ++v)
            A_reg[r][v] = Ag[rowbase + r * 16 + 4 * g + v];

    float bestv[2][4]; int bidx[2][4];
    #pragma unroll
    for (int r = 0; r < 2; ++r)
        #pragma unroll
        for (int v = 0; v < 4; ++v) { bestv[r][v] = INFINITY; bidx[r][v] = 0; }

    // fragment-order tables: lane l's data for tile t at t*1024 + ks*512 + l*8
    const _Float16* eh = ehi + (size_t)(k0 >> 4) * 1024 + (size_t)l * 8;
    const _Float16* el = elo + (size_t)(k0 >> 4) * 1024 + (size_t)l * 8;

    f16x8 bh0[2], bh1[2], bl0[2], bl1[2];
    float b2r[2];
    unsigned off[2] = {0u, 1024u};            // halves; += 2048 per reload
    int b2i[2] = {c16, 16 + c16};             // b2sh index; += 32 per reload
    int cbase = k0 + c16;                     // strictly increasing code index
    const f32x4 fzero = {0.f, 0.f, 0.f, 0.f};

#define LOADB(sl) do {                                       \
        const unsigned _o = off[sl];                         \
        bh0[sl] = *(const f16x8*)(eh + _o);                  \
        bh1[sl] = *(const f16x8*)(eh + _o + 512);            \
        bl0[sl] = *(const f16x8*)(el + _o);                  \
        bl1[sl] = *(const f16x8*)(el + _o + 512);            \
        b2r[sl] = b2sh[b2i[sl] & (KSPL - 1)];                \
        off[sl] += 2048u;                                    \
        b2i[sl] += 32;                                       \
    } while (0)

#define COMP(sl) do {                                                             \
        f32x4 acc1[2], acc2[2];                                                   \
        _Pragma("unroll")                                                         \
        for (int r = 0; r < 2; ++r) {                                             \
            acc1[r] = __builtin_amdgcn_mfma_f32_16x16x32_f16(xh[r][0], bh0[sl], fzero,   0, 0, 0); \
            acc1[r] = __builtin_amdgcn_mfma_f32_16x16x32_f16(xh[r][1], bh1[sl], acc1[r], 0, 0, 0); \
            acc2[r] = __builtin_amdgcn_mfma_f32_16x16x32_f16(xl[r][0], bh0[sl], fzero,   0, 0, 0); \
            acc2[r] = __builtin_amdgcn_mfma_f32_16x16x32_f16(xl[r][1], bh1[sl], acc2[r], 0, 0, 0); \
            acc2[r] = __builtin_amdgcn_mfma_f32_16x16x32_f16(xh[r][0], bl0[sl], acc2[r], 0, 0, 0); \
            acc2[r] = __builtin_amdgcn_mfma_f32_16x16x32_f16(xh[r][1], bl1[sl], acc2[r], 0, 0, 0); \
        }                                                                         \
        _Pragma("unroll")                                                         \
        for (int r = 0; r < 2; ++r) {                                             \
            _Pragma("unroll")                                                     \
            for (int v = 0; v < 4; ++v) {                                         \
                float dotc = fmaf(acc2[r][v], 0x1p-12f, acc1[r][v]);              \
                float t = A_reg[r][v] + b2r[sl];                                  \
                float sc = fmaf(dotc, -0x1p-19f, t);                              \
                bool lt = sc < bestv[r][v];   /* strict <: lowest idx on tie */   \
                bestv[r][v] = lt ? sc : bestv[r][v];                              \
                bidx[r][v]  = lt ? cbase : bidx[r][v];                            \
            }                                                                     \
        }                                                                         \
        cbase += 16;                                                              \
    } while (0)

    LOADB(0);
    LOADB(1);

    #pragma unroll 1
    for (int s = 0; s < STEPS; s += 2) {
        COMP(0);
        LOADB(0);       // prefetch stv = s+2 (reads past end on last iter: discarded)
        COMP(1);
        LOADB(1);       // prefetch stv = s+3
    }
#undef LOADB
#undef COMP

    // reduce (value, then lowest index) across the 16 lanes of each k-group
    #pragma unroll
    for (int off2 = 1; off2 < 16; off2 <<= 1) {
        #pragma unroll
        for (int r = 0; r < 2; ++r)
            #pragma unroll
            for (int v = 0; v < 4; ++v) {
                float ob = __shfl_xor(bestv[r][v], off2);
                int   oi = __shfl_xor(bidx[r][v], off2);
                if (ob < bestv[r][v] || (ob == bestv[r][v] && oi < bidx[r][v])) {
                    bestv[r][v] = ob; bidx[r][v] = oi;
                }
            }
    }
    if (c16 == 0) {
        #pragma unroll
        for (int r = 0; r < 2; ++r)
            #pragma unroll
            for (int v = 0; v < 4; ++v) {
                const int row = rowbase + r * 16 + 4 * g + v;
                unsigned long long key =
                    ((unsigned long long)__float_as_uint(bestv[r][v]) << 32) |
                    (unsigned)bidx[r][v];
                atomicMin(&keys[row], key);
            }
    }
}

// ---------------- Kernel H: LDS histogram of codes ----------------
__global__ __launch_bounds__(1024)
void vq_hist(const unsigned long long* __restrict__ keys,
             unsigned* __restrict__ counts) {
    __shared__ unsigned h[KCODE];
    const int tid = threadIdx.x;
    #pragma unroll
    for (int j = 0; j < 4; ++j) h[tid + j * 1024] = 0u;
    __syncthreads();
    const int row = blockIdx.x * 1024 + tid;      // grid 64 x 1024
    const unsigned k = (unsigned)(keys[row] & 0xFFFFFFFFu);
    atomicAdd(&h[k], 1u);
    __syncthreads();
    #pragma unroll
    for (int j = 0; j < 4; ++j) {
        unsigned v = h[tid + j * 1024];
        if (v) atomicAdd(&counts[tid + j * 1024], v);
    }
}

// ---------------- Kernel S: exclusive scan -> offsets, cursor ----------------
__global__ __launch_bounds__(1024)
void vq_scan(const unsigned* __restrict__ counts,
             unsigned* __restrict__ offs, unsigned* __restrict__ cursor) {
    __shared__ unsigned red[1024];
    const int tid = threadIdx.x;
    unsigned c[4], tot = 0;
    #pragma unroll
    for (int j = 0; j < 4; ++j) { c[j] = counts[tid * 4 + j]; tot += c[j]; }
    red[tid] = tot;
    __syncthreads();
    for (int s = 1; s < 1024; s <<= 1) {
        unsigned v = (tid >= s) ? red[tid - s] : 0u;
        __syncthreads();
        red[tid] += v;
        __syncthreads();
    }
    unsigned base = red[tid] - tot;   // exclusive over thread blocks of 4
    #pragma unroll
    for (int j = 0; j < 4; ++j) {
        offs[tid * 4 + j] = base;
        cursor[tid * 4 + j] = base;
        base += c[j];
    }
}

// ---------------- Kernel T: scatter row ids into code-sorted order ----------------
__global__ __launch_bounds__(256)
void vq_scatter(const unsigned long long* __restrict__ keys,
                unsigned* __restrict__ cursor, unsigned* __restrict__ order) {
    const int row = blockIdx.x * 256 + threadIdx.x;
    const unsigned k = (unsigned)(keys[row] & 0xFFFFFFFFu);
    const unsigned slot = atomicAdd(&cursor[k], 1u);
    order[slot] = row;
}

// ---------------- Kernel W: per-code segment sum -> new_ema_w, counts ----------------
__global__ __launch_bounds__(256)
void vq_dw(const float* __restrict__ x, const float* __restrict__ ema_w,
           const unsigned* __restrict__ counts, const unsigned* __restrict__ offs,
           const unsigned* __restrict__ order, float* __restrict__ out) {
    const int tid = threadIdx.x;
    const int lane = tid & 63;
    const int k = blockIdx.x * 4 + (tid >> 6);    // grid 1024 x 256
    const unsigned cnt = counts[k];
    const unsigned off = offs[k];
    float acc = 0.f;
    for (unsigned i = 0; i < cnt; ++i) {
        const unsigned row = order[off + i];
        acc += x[(size_t)row * DDIM + lane];
    }
    const float e = ema_w[(size_t)k * DDIM + lane];
    out[O_NEW + (size_t)k * DDIM + lane] = fmaf(0.01f, acc, 0.99f * e);
    if (lane == 0) out[O_CS + k] = (float)cnt;
}

// ---------------- Kernel C: gather + ST output + loss partials (atomic-free) ----------------
__global__ __launch_bounds__(256)
void vq_gather2(const float* __restrict__ x, const float* __restrict__ w,
                const unsigned long long* __restrict__ keys,
                float* __restrict__ out, float* __restrict__ lpart) {
    const int tid = threadIdx.x;
    const int l16 = tid & 15;
    const int row = blockIdx.x * 16 + (tid >> 4);
    const int k = (int)(unsigned)(keys[row] & 0xFFFFFFFFu);
    if (l16 == 0) out[O_IDX + row] = (float)k;

    const float4 w4 = ((const float4*)(w + (size_t)k * DDIM))[l16];
    const float4 x4 = ((const float4*)(x + (size_t)row * DDIM))[l16];
    float4 o;
    o.x = x4.x + (w4.x - x4.x);
    o.y = x4.y + (w4.y - x4.y);
    o.z = x4.z + (w4.z - x4.z);
    o.w = x4.w + (w4.w - x4.w);
    ((float4*)(out + O_Q + (size_t)row * DDIM))[l16] = o;
    float dx = w4.x - x4.x, dy = w4.y - x4.y, dz = w4.z - x4.z, dw_ = w4.w - x4.w;
    float e = dx * dx + dy * dy + dz * dz + dw_ * dw_;
    #pragma unroll
    for (int off = 32; off > 0; off >>= 1) e += __shfl_down(e, off);
    if ((tid & 63) == 0) lpart[blockIdx.x * 4 + (tid >> 6)] = e;
}

// ---------------- Kernel D: loss reduce + Laplace smoothing ----------------
__global__ __launch_bounds__(1024)
void vq_cs(const float* __restrict__ ecs, const float* __restrict__ lpart,
           float* __restrict__ out) {
    __shared__ float red[1024];
    __shared__ double dred[1024];
    const int tid = threadIdx.x;
    double dl = 0.0;
    #pragma unroll
    for (int j = 0; j < 16; ++j) dl += (double)lpart[j * 1024 + tid];
    dred[tid] = dl;
    float cs[4];
    float local = 0.f;
    #pragma unroll
    for (int j = 0; j < 4; ++j) {
        int k = j * 1024 + tid;
        float cnt = out[O_CS + k];
        cs[j] = ecs[k] * 0.99f + 0.01f * cnt;
        local += cs[j];
    }
    red[tid] = local;
    for (int s = 512; s > 0; s >>= 1) {
        __syncthreads();
        if (tid < s) { red[tid] += red[tid + s]; dred[tid] += dred[tid + s]; }
    }
    __syncthreads();
    const float n = red[0];
    const float denom = n + 0.04096f;
    #pragma unroll
    for (int j = 0; j < 4; ++j) {
        int k = j * 1024 + tid;
        out[O_CS + k] = (cs[j] + 1e-5f) / denom * n;
    }
    if (tid == 0) out[O_LOSS] = 1.25f * (float)(dred[0] / 4194304.0);
}

// ---------------- Kernel E: new_weight = new_ema_w / cs ----------------
__global__ __launch_bounds__(256)
void vq_final(float* __restrict__ out) {
    int i = blockIdx.x * 256 + threadIdx.x;
    if (i >= KCODE * DDIM) return;
    int k = i >> 6;
    out[O_NW + i] = out[O_NEW + i] / out[O_CS + k];
}

extern "C" void kernel_launch(void* const* d_in, const int* in_sizes, int n_in,
                              void* d_out, int out_size, void* d_ws, size_t ws_size,
                              hipStream_t stream) {
    (void)in_sizes; (void)n_in; (void)out_size; (void)d_ws; (void)ws_size;
    const float* x    = (const float*)d_in[0];
    const float* w    = (const float*)d_in[1];
    const float* ecs  = (const float*)d_in[2];
    const float* emaw = (const float*)d_in[3];
    float* out = (float*)d_out;

    const _Float16* ehi = (const _Float16*)out;
    const _Float16* elo = ((const _Float16*)out) + 262144;
    const float*    Ag  = out + O_A;
    unsigned long long* keys = (unsigned long long*)(out + O_NW + 1);
    unsigned* counts = (unsigned*)(out + O_CNT);
    unsigned* offs   = (unsigned*)(out + O_OFF);
    unsigned* cursor = (unsigned*)(out + O_CUR);
    unsigned* order  = (unsigned*)(out + O_ORD);
    float*    lpart  = out + O_LP;

    vq_prep       <<<1024, 256, 0, stream>>>(x, w, out, keys);
    vq_argmin_mfma<<<dim3(512, NSPLIT), 256, 0, stream>>>(x, ehi, elo, Ag,
                                                          out + O_B2, keys);
    vq_hist       <<<64, 1024, 0, stream>>>(keys, counts);
    vq_scan       <<<1, 1024, 0, stream>>>(counts, offs, cursor);
    vq_scatter    <<<256, 256, 0, stream>>>(keys, cursor, order);
    vq_dw         <<<1024, 256, 0, stream>>>(x, emaw, counts, offs, order, out);
    vq_gather2    <<<4096, 256, 0, stream>>>(x, w, keys, out, lpart);
    vq_cs         <<<1, 1024, 0, stream>>>(ecs, lpart, out);
    vq_final      <<<1024, 256, 0, stream>>>(out);
}

// Round 10
// 178.975 us; speedup vs baseline: 2.1819x; 1.0320x over previous
//
#include <hip/hip_runtime.h>
#include <math.h>

#define NROWS 65536
#define DDIM  64
#define KCODE 4096
#define NSPLIT 2
#define KSPL  (KCODE / NSPLIT)
#define STEPS (KSPL / 16)          // 128

// output layout (float offsets), concatenated in reference return order
#define O_Q    0           // quantized_st [B,T,D] = 4194304
#define O_LOSS 4194304     // loss scalar
#define O_IDX  4194305     // encoding_indices [B,T] = 65536 (floats)
#define O_NW   4259841     // new_weight [K,D] = 262144
#define O_CS   4521985     // cs [K] = 4096
#define O_NEW  4526081     // new_ema_w [K,D] = 262144

// scratch inside O_Q (dead once vq_gather2 writes Q rows):
//   E     : halves [0, 524288) — interleaved fragment-tile order, 2048/tile:
//           tile*2048 + (hi?0:1024) + (j>>5)*512 + ((j>>3)&3)*128 + (k&15)*8 + (j&7)
//   A     : floats [262144, 327680)
//   B2    : floats [327680, 331776)
//   counts: u32 @ 1000000; offs: u32 @ 1010000; cursor: u32 @ 1020000
//   order : u32 @ 1030000
// scratch inside O_NW (clobbered only by vq_final):
//   keys  : u64[65536] at float offset O_NW+1
//   lpart : f32[16384] at float offset O_NW+131074
#define O_A      262144
#define O_B2     327680
#define O_CNT   1000000
#define O_OFF   1010000
#define O_CUR   1020000
#define O_ORD   1030000
#define O_LP    (O_NW + 131074)

typedef _Float16 f16x8 __attribute__((ext_vector_type(8)));
typedef float    f32x4 __attribute__((ext_vector_type(4)));

// ---------------- Kernel A: init + splits + norms + key/count init ----------------
__global__ __launch_bounds__(256)
void vq_prep(const float* __restrict__ x, const float* __restrict__ w,
             float* __restrict__ out, unsigned long long* __restrict__ keys) {
    int i = blockIdx.x * 256 + threadIdx.x;   // grid = 262144 threads exactly
    // interleaved fragment-tile table: hi and lo fragments of a 16-code tile
    // sit in one 4KB block -> argmin loads = 1 uniform pointer + imm offsets
    {
        const int k = i >> 6, j = i & 63;
        float E = w[i] * 4096.0f;             // scaled f16 split of codes
        _Float16 h = (_Float16)E;
        float r = E - (float)h;
        _Float16 lo = (_Float16)(r * 4096.0f);
        const size_t pos = (size_t)(k >> 4) * 2048 + (size_t)(j >> 5) * 512
                         + (size_t)((j >> 3) & 3) * 128 + (size_t)(k & 15) * 8
                         + (size_t)(j & 7);
        ((_Float16*)out)[pos] = h;            // hi half of tile block
        ((_Float16*)out)[pos + 1024] = lo;    // lo half of tile block
    }
    if (i < NROWS) keys[i] = 0xFFFFFFFFFFFFFFFFULL;
    if (i < KCODE) ((unsigned*)(out + O_CNT))[i] = 0u;
    // x-norms (EXACT same per-row summation order as validated rounds)
    if ((i & 3) == 0) {
        const int row = i >> 2;
        const float4* xr = (const float4*)(x + (size_t)row * DDIM);
        float ax = 0.f, ay = 0.f, az = 0.f, aw = 0.f;
        #pragma unroll
        for (int j = 0; j < 16; ++j) {
            float4 v = xr[j];
            ax += v.x * v.x; ay += v.y * v.y; az += v.z * v.z; aw += v.w * v.w;
        }
        out[O_A + row] = (ax + ay) + (az + aw);
    }
    // w-norms
    if ((i & 63) == 0) {
        const int k = i >> 6;
        const float4* wr = (const float4*)(w + (size_t)k * DDIM);
        float ax = 0.f, ay = 0.f, az = 0.f, aw = 0.f;
        #pragma unroll
        for (int j = 0; j < 16; ++j) {
            float4 v = wr[j];
            ax += v.x * v.x; ay += v.y * v.y; az += v.z * v.z; aw += v.w * v.w;
        }
        out[O_B2 + k] = (ax + ay) + (az + aw);
    }
}

__device__ inline void split8(float4 a, float4 b, f16x8& hi, f16x8& lo) {
    float vv[8] = {a.x, a.y, a.z, a.w, b.x, b.y, b.z, b.w};
    #pragma unroll
    for (int j = 0; j < 8; ++j) {
        float X = vv[j] * 256.0f;           // x*2^8
        _Float16 h = (_Float16)X;
        float r = X - (float)h;             // exact (Sterbenz)
        hi[j] = h;
        lo[j] = (_Float16)(r * 4096.0f);    // residual*2^12
    }
}

// ---------------- Kernel B: MFMA fused score + argmin (R=4 rows amortized) ----------------
// grid (256, 2) x 256 thr (4 waves) = 512 blocks (2/CU). Wave owns 64 rows
// (4 row-subtiles); scans KSPL=2048 codes in 128 steps of 16. Per step the 4
// B loads (uniform ptr + imm offsets) + bookkeeping feed 24 MFMAs / 16 scores
// -> per-score VALU overhead halved vs round 9 (additive-issue model: dur ~
// MFMA 46.6us + VALU + idle; this cuts the VALU term).
__global__ __launch_bounds__(256, 2)
void vq_argmin_mfma(const float* __restrict__ x,
                    const _Float16* __restrict__ etab,
                    const float* __restrict__ Ag,
                    const float* __restrict__ b2g,
                    unsigned long long* __restrict__ keys) {
    __shared__ __align__(16) float b2sh[KSPL + 128];   // pad: dead prefetch reads
    const int tid = threadIdx.x;
    const int k0  = blockIdx.y * KSPL;
    #pragma unroll
    for (int j = 0; j < KSPL / 1024; ++j)
        ((float4*)b2sh)[tid + j * 256] = ((const float4*)(b2g + k0))[tid + j * 256];
    __syncthreads();

    const int l   = tid & 63;
    const int w   = tid >> 6;
    const int g   = l >> 4;
    const int c16 = l & 15;
    const int rowbase = blockIdx.x * 256 + w * 64;

    // A-operand fragments for 4 row-subtiles
    f16x8 xh[4][2], xl[4][2];
    #pragma unroll
    for (int r = 0; r < 4; ++r) {
        const float* xr = x + (size_t)(rowbase + r * 16 + c16) * DDIM + g * 8;
        float4 a0 = *(const float4*)(xr);
        float4 a1 = *(const float4*)(xr + 4);
        float4 a2 = *(const float4*)(xr + 32);
        float4 a3 = *(const float4*)(xr + 36);
        split8(a0, a1, xh[r][0], xl[r][0]);
        split8(a2, a3, xh[r][1], xl[r][1]);
    }
    float A_reg[4][4];
    #pragma unroll
    for (int r = 0; r < 4; ++r)
        #pragma unroll
        for (int v = 0; v < 4; ++v)
            A_reg[r][v] = Ag[rowbase + r * 16 + 4 * g + v];

    float bestv[4][4]; int bidx[4][4];
    #pragma unroll
    for (int r = 0; r < 4; ++r)
        #pragma unroll
        for (int v = 0; v < 4; ++v) { bestv[r][v] = INFINITY; bidx[r][v] = 0; }

    // interleaved table: tile t block at t*2048; lane fragment at +l*8;
    // {bh0,bh1,bl0,bl1} at imm offsets 0/512/1024/1536 halves
    const _Float16* p[2];
    p[0] = etab + (size_t)(k0 >> 4) * 2048 + (size_t)l * 8;
    p[1] = p[0] + 2048;

    f16x8 bh0[2], bh1[2], bl0[2], bl1[2];
    float b2r[2];
    int b2i[2] = {c16, 16 + c16};
    int cbase = k0 + c16;                     // strictly increasing code index
    const f32x4 fzero = {0.f, 0.f, 0.f, 0.f};

#define LOADB(sl) do {                                       \
        bh0[sl] = *(const f16x8*)(p[sl]);                    \
        bh1[sl] = *(const f16x8*)(p[sl] + 512);              \
        bl0[sl] = *(const f16x8*)(p[sl] + 1024);             \
        bl1[sl] = *(const f16x8*)(p[sl] + 1536);             \
        b2r[sl] = b2sh[b2i[sl]];                             \
        p[sl] += 4096;                                       \
        b2i[sl] += 32;                                       \
    } while (0)

#define COMP(sl) do {                                                             \
        _Pragma("unroll")                                                         \
        for (int r = 0; r < 4; ++r) {                                             \
            f32x4 acc1, acc2;                                                     \
            acc1 = __builtin_amdgcn_mfma_f32_16x16x32_f16(xh[r][0], bh0[sl], fzero, 0, 0, 0); \
            acc1 = __builtin_amdgcn_mfma_f32_16x16x32_f16(xh[r][1], bh1[sl], acc1,  0, 0, 0); \
            acc2 = __builtin_amdgcn_mfma_f32_16x16x32_f16(xl[r][0], bh0[sl], fzero, 0, 0, 0); \
            acc2 = __builtin_amdgcn_mfma_f32_16x16x32_f16(xl[r][1], bh1[sl], acc2,  0, 0, 0); \
            acc2 = __builtin_amdgcn_mfma_f32_16x16x32_f16(xh[r][0], bl0[sl], acc2,  0, 0, 0); \
            acc2 = __builtin_amdgcn_mfma_f32_16x16x32_f16(xh[r][1], bl1[sl], acc2,  0, 0, 0); \
            _Pragma("unroll")                                                     \
            for (int v = 0; v < 4; ++v) {                                         \
                float dotc = fmaf(acc2[v], 0x1p-12f, acc1[v]);                    \
                float t = A_reg[r][v] + b2r[sl];                                  \
                float sc = fmaf(dotc, -0x1p-19f, t);                              \
                bool lt = sc < bestv[r][v];   /* strict <: lowest idx on tie */   \
                bestv[r][v] = lt ? sc : bestv[r][v];                              \
                bidx[r][v]  = lt ? cbase : bidx[r][v];                            \
            }                                                                     \
        }                                                                         \
        cbase += 16;                                                              \
    } while (0)

    LOADB(0);
    LOADB(1);

    #pragma unroll 1
    for (int s = 0; s < STEPS; s += 2) {
        COMP(0);
        LOADB(0);       // prefetch s+2 (reads past end on last iters: discarded)
        COMP(1);
        LOADB(1);       // prefetch s+3
    }
#undef LOADB
#undef COMP

    // reduce (value, then lowest index) across the 16 lanes of each k-group
    #pragma unroll
    for (int off2 = 1; off2 < 16; off2 <<= 1) {
        #pragma unroll
        for (int r = 0; r < 4; ++r)
            #pragma unroll
            for (int v = 0; v < 4; ++v) {
                float ob = __shfl_xor(bestv[r][v], off2);
                int   oi = __shfl_xor(bidx[r][v], off2);
                if (ob < bestv[r][v] || (ob == bestv[r][v] && oi < bidx[r][v])) {
                    bestv[r][v] = ob; bidx[r][v] = oi;
                }
            }
    }
    if (c16 == 0) {
        #pragma unroll
        for (int r = 0; r < 4; ++r)
            #pragma unroll
            for (int v = 0; v < 4; ++v) {
                const int row = rowbase + r * 16 + 4 * g + v;
                unsigned long long key =
                    ((unsigned long long)__float_as_uint(bestv[r][v]) << 32) |
                    (unsigned)bidx[r][v];
                atomicMin(&keys[row], key);
            }
    }
}

// ---------------- Kernel H: LDS histogram of codes ----------------
__global__ __launch_bounds__(1024)
void vq_hist(const unsigned long long* __restrict__ keys,
             unsigned* __restrict__ counts) {
    __shared__ unsigned h[KCODE];
    const int tid = threadIdx.x;
    #pragma unroll
    for (int j = 0; j < 4; ++j) h[tid + j * 1024] = 0u;
    __syncthreads();
    const int row = blockIdx.x * 1024 + tid;      // grid 64 x 1024
    const unsigned k = (unsigned)(keys[row] & 0xFFFFFFFFu);
    atomicAdd(&h[k], 1u);
    __syncthreads();
    #pragma unroll
    for (int j = 0; j < 4; ++j) {
        unsigned v = h[tid + j * 1024];
        if (v) atomicAdd(&counts[tid + j * 1024], v);
    }
}

// ---------------- Kernel S: exclusive scan -> offsets, cursor ----------------
__global__ __launch_bounds__(1024)
void vq_scan(const unsigned* __restrict__ counts,
             unsigned* __restrict__ offs, unsigned* __restrict__ cursor) {
    __shared__ unsigned red[1024];
    const int tid = threadIdx.x;
    unsigned c[4], tot = 0;
    #pragma unroll
    for (int j = 0; j < 4; ++j) { c[j] = counts[tid * 4 + j]; tot += c[j]; }
    red[tid] = tot;
    __syncthreads();
    for (int s = 1; s < 1024; s <<= 1) {
        unsigned v = (tid >= s) ? red[tid - s] : 0u;
        __syncthreads();
        red[tid] += v;
        __syncthreads();
    }
    unsigned base = red[tid] - tot;   // exclusive over thread blocks of 4
    #pragma unroll
    for (int j = 0; j < 4; ++j) {
        offs[tid * 4 + j] = base;
        cursor[tid * 4 + j] = base;
        base += c[j];
    }
}

// ---------------- Kernel T: scatter row ids into code-sorted order ----------------
__global__ __launch_bounds__(256)
void vq_scatter(const unsigned long long* __restrict__ keys,
                unsigned* __restrict__ cursor, unsigned* __restrict__ order) {
    const int row = blockIdx.x * 256 + threadIdx.x;
    const unsigned k = (unsigned)(keys[row] & 0xFFFFFFFFu);
    const unsigned slot = atomicAdd(&cursor[k], 1u);
    order[slot] = row;
}

// ---------------- Kernel W: per-code segment sum -> new_ema_w, counts ----------------
__global__ __launch_bounds__(256)
void vq_dw(const float* __restrict__ x, const float* __restrict__ ema_w,
           const unsigned* __restrict__ counts, const unsigned* __restrict__ offs,
           const unsigned* __restrict__ order, float* __restrict__ out) {
    const int tid = threadIdx.x;
    const int lane = tid & 63;
    const int k = blockIdx.x * 4 + (tid >> 6);    // grid 1024 x 256
    const unsigned cnt = counts[k];
    const unsigned off = offs[k];
    float acc = 0.f;
    for (unsigned i = 0; i < cnt; ++i) {
        const unsigned row = order[off + i];
        acc += x[(size_t)row * DDIM + lane];
    }
    const float e = ema_w[(size_t)k * DDIM + lane];
    out[O_NEW + (size_t)k * DDIM + lane] = fmaf(0.01f, acc, 0.99f * e);
    if (lane == 0) out[O_CS + k] = (float)cnt;
}

// ---------------- Kernel C: gather + ST output + loss partials (atomic-free) ----------------
__global__ __launch_bounds__(256)
void vq_gather2(const float* __restrict__ x, const float* __restrict__ w,
                const unsigned long long* __restrict__ keys,
                float* __restrict__ out, float* __restrict__ lpart) {
    const int tid = threadIdx.x;
    const int l16 = tid & 15;
    const int row = blockIdx.x * 16 + (tid >> 4);
    const int k = (int)(unsigned)(keys[row] & 0xFFFFFFFFu);
    if (l16 == 0) out[O_IDX + row] = (float)k;

    const float4 w4 = ((const float4*)(w + (size_t)k * DDIM))[l16];
    const float4 x4 = ((const float4*)(x + (size_t)row * DDIM))[l16];
    float4 o;
    o.x = x4.x + (w4.x - x4.x);
    o.y = x4.y + (w4.y - x4.y);
    o.z = x4.z + (w4.z - x4.z);
    o.w = x4.w + (w4.w - x4.w);
    ((float4*)(out + O_Q + (size_t)row * DDIM))[l16] = o;
    float dx = w4.x - x4.x, dy = w4.y - x4.y, dz = w4.z - x4.z, dw_ = w4.w - x4.w;
    float e = dx * dx + dy * dy + dz * dz + dw_ * dw_;
    #pragma unroll
    for (int off = 32; off > 0; off >>= 1) e += __shfl_down(e, off);
    if ((tid & 63) == 0) lpart[blockIdx.x * 4 + (tid >> 6)] = e;
}

// ---------------- Kernel D: loss reduce + Laplace smoothing ----------------
__global__ __launch_bounds__(1024)
void vq_cs(const float* __restrict__ ecs, const float* __restrict__ lpart,
           float* __restrict__ out) {
    __shared__ float red[1024];
    __shared__ double dred[1024];
    const int tid = threadIdx.x;
    double dl = 0.0;
    #pragma unroll
    for (int j = 0; j < 16; ++j) dl += (double)lpart[j * 1024 + tid];
    dred[tid] = dl;
    float cs[4];
    float local = 0.f;
    #pragma unroll
    for (int j = 0; j < 4; ++j) {
        int k = j * 1024 + tid;
        float cnt = out[O_CS + k];
        cs[j] = ecs[k] * 0.99f + 0.01f * cnt;
        local += cs[j];
    }
    red[tid] = local;
    for (int s = 512; s > 0; s >>= 1) {
        __syncthreads();
        if (tid < s) { red[tid] += red[tid + s]; dred[tid] += dred[tid + s]; }
    }
    __syncthreads();
    const float n = red[0];
    const float denom = n + 0.04096f;
    #pragma unroll
    for (int j = 0; j < 4; ++j) {
        int k = j * 1024 + tid;
        out[O_CS + k] = (cs[j] + 1e-5f) / denom * n;
    }
    if (tid == 0) out[O_LOSS] = 1.25f * (float)(dred[0] / 4194304.0);
}

// ---------------- Kernel E: new_weight = new_ema_w / cs ----------------
__global__ __launch_bounds__(256)
void vq_final(float* __restrict__ out) {
    int i = blockIdx.x * 256 + threadIdx.x;
    if (i >= KCODE * DDIM) return;
    int k = i >> 6;
    out[O_NW + i] = out[O_NEW + i] / out[O_CS + k];
}

extern "C" void kernel_launch(void* const* d_in, const int* in_sizes, int n_in,
                              void* d_out, int out_size, void* d_ws, size_t ws_size,
                              hipStream_t stream) {
    (void)in_sizes; (void)n_in; (void)out_size; (void)d_ws; (void)ws_size;
    const float* x    = (const float*)d_in[0];
    const float* w    = (const float*)d_in[1];
    const float* ecs  = (const float*)d_in[2];
    const float* emaw = (const float*)d_in[3];
    float* out = (float*)d_out;

    const _Float16* etab = (const _Float16*)out;
    const float*    Ag   = out + O_A;
    unsigned long long* keys = (unsigned long long*)(out + O_NW + 1);
    unsigned* counts = (unsigned*)(out + O_CNT);
    unsigned* offs   = (unsigned*)(out + O_OFF);
    unsigned* cursor = (unsigned*)(out + O_CUR);
    unsigned* order  = (unsigned*)(out + O_ORD);
    float*    lpart  = out + O_LP;

    vq_prep       <<<1024, 256, 0, stream>>>(x, w, out, keys);
    vq_argmin_mfma<<<dim3(256, NSPLIT), 256, 0, stream>>>(x, etab, Ag,
                                                          out + O_B2, keys);
    vq_hist       <<<64, 1024, 0, stream>>>(keys, counts);
    vq_scan       <<<1, 1024, 0, stream>>>(counts, offs, cursor);
    vq_scatter    <<<256, 256, 0, stream>>>(keys, cursor, order);
    vq_dw         <<<1024, 256, 0, stream>>>(x, emaw, counts, offs, order, out);
    vq_gather2    <<<4096, 256, 0, stream>>>(x, w, keys, out, lpart);
    vq_cs         <<<1, 1024, 0, stream>>>(ecs, lpart, out);
    vq_final      <<<1024, 256, 0, stream>>>(out);
}